// Round 1
// baseline (1456.609 us; speedup 1.0000x reference)
//
#include <hip/hip_runtime.h>
#include <math.h>

// ---------------------------------------------------------------------------
// Spherical CNN regression forward (MAXL=3, 2 layers, TAU_IN=16, TAU_H=32).
// One 128-thread block per batch element; all per-element state in LDS.
// CG coefficients computed on-device into d_ws by a tiny init kernel.
// ---------------------------------------------------------------------------

__device__ __forceinline__ double dfact(int n) {
    double r = 1.0;
    for (int i = 2; i <= n; ++i) r *= (double)i;
    return r;
}

// Dense CG table: [l1][l2][L][m1+l1][m2+l2][M+L], each of last 3 dims = 7.
// Size 4*4*4*7*7*7 = 21952 floats = 87,808 bytes (lives in d_ws).
#define CG_TOTAL (4 * 4 * 4 * 7 * 7 * 7)

__global__ void cg_init_kernel(float* __restrict__ cg) {
    for (int i = threadIdx.x; i < CG_TOTAL; i += blockDim.x) cg[i] = 0.0f;
    __syncthreads();
    for (int t = threadIdx.x; t < 64; t += blockDim.x) {
        int l1 = t >> 4, l2 = (t >> 2) & 3, L = t & 3;
        if (L < abs(l1 - l2) || L > l1 + l2) continue;
        for (int i = 0; i <= 2 * l1; ++i) {
            int m1 = i - l1;
            for (int j = 0; j <= 2 * l2; ++j) {
                int m2 = j - l2;
                int M = m1 + m2;
                if (M < -L || M > L) continue;
                double pre = sqrt((2.0 * L + 1.0) * dfact(l1 + l2 - L) * dfact(l1 - l2 + L) *
                                  dfact(-l1 + l2 + L) / dfact(l1 + l2 + L + 1));
                pre *= sqrt(dfact(L + M) * dfact(L - M) * dfact(l1 - m1) * dfact(l1 + m1) *
                            dfact(l2 - m2) * dfact(l2 + m2));
                double s = 0.0;
                for (int k = 0; k <= l1 + l2 - L; ++k) {
                    int u2 = l1 - m1 - k, u3 = l2 + m2 - k;
                    int u4 = L - l2 + m1 + k, u5 = L - l1 - m2 + k;
                    if (u2 < 0 || u3 < 0 || u4 < 0 || u5 < 0) continue;
                    double d = dfact(k) * dfact(l1 + l2 - L - k) * dfact(u2) * dfact(u3) *
                               dfact(u4) * dfact(u5);
                    s += ((k & 1) ? -1.0 : 1.0) / d;
                }
                cg[((((l1 * 4 + l2) * 4 + L) * 7 + i) * 7 + j) * 7 + (M + L)] = (float)(pre * s);
            }
        }
    }
}

// Pair tables: for each L, the (l1,l2) blocks in reference concatenation order.
__constant__ int c_PS[5] = {0, 4, 13, 24, 34};
__constant__ unsigned char c_P1[34] = {
    0, 1, 2, 3,
    0, 1, 1, 1, 2, 2, 2, 3, 3,
    0, 1, 1, 1, 2, 2, 2, 2, 3, 3, 3,
    0, 1, 1, 2, 2, 2, 3, 3, 3, 3};
__constant__ unsigned char c_P2[34] = {
    0, 1, 2, 3,
    1, 0, 1, 2, 1, 2, 3, 2, 3,
    2, 1, 2, 3, 0, 1, 2, 3, 1, 2, 3,
    3, 2, 3, 1, 2, 3, 0, 1, 2, 3};

__device__ __forceinline__ float2 cfma(float2 a, float2 b, float2 acc) {
    acc.x += a.x * b.x - a.y * b.y;
    acc.y += a.x * b.y + a.y * b.x;
    return acc;
}

__global__ void __launch_bounds__(128) sph_fwd(
    const float* __restrict__ p0, const float* __restrict__ p1,
    const float* __restrict__ p2, const float* __restrict__ p3,
    const float* __restrict__ Wi0, const float* __restrict__ Wi1,
    const float* __restrict__ Wi2, const float* __restrict__ Wi3,
    const float* __restrict__ Wh00, const float* __restrict__ Wh01,
    const float* __restrict__ Wh02, const float* __restrict__ Wh03,
    const float* __restrict__ Wh10, const float* __restrict__ Wh11,
    const float* __restrict__ Wh12, const float* __restrict__ Wh13,
    const float* __restrict__ W1, const float* __restrict__ b1,
    const float* __restrict__ W2, const float* __restrict__ b2,
    const float* __restrict__ cg, float* __restrict__ out) {
    // LDS: hidden/new_hidden as [slot][channel] float2; slot = l*l + m_idx
    // (slots: l=0 -> 0, l=1 -> 1..3, l=2 -> 4..8, l=3 -> 9..15).
    __shared__ float2 sh_hidden[16][32];
    __shared__ float2 sh_new[16][32];
    __shared__ float2 sh_buf[2240];  // parts staging / per-L CG products / MLP scratch

    const int tid = threadIdx.x;
    const int b = blockIdx.x;

    // ---------------- Phase 0: stage parts [16 slots][16 taus] into LDS ------
    for (int idx = tid; idx < 16 * 16; idx += 128) {
        int slot = idx >> 4, k = idx & 15;
        int l = (slot >= 9) + (slot >= 4) + (slot >= 1);
        int m = slot - l * l;
        const float* src = (l == 0) ? p0 : (l == 1) ? p1 : (l == 2) ? p2 : p3;
        src += ((size_t)(b * (2 * l + 1) + m) * 16 + k) * 2;
        sh_buf[idx] = make_float2(src[0], src[1]);
    }
    __syncthreads();

    // ---------------- Phase 1: input matmul (tau_in=16 -> tau_h=32) ----------
#pragma unroll
    for (int r = 0; r < 4; ++r) {
        int oi = tid + 128 * r;
        int slot = oi >> 5, c = oi & 31;
        int l = (slot >= 9) + (slot >= 4) + (slot >= 1);
        const float* W = (l == 0) ? Wi0 : (l == 1) ? Wi1 : (l == 2) ? Wi2 : Wi3;
        const float2* prow = &sh_buf[slot * 16];
        float2 acc = make_float2(0.f, 0.f);
        for (int k = 0; k < 16; ++k) {
            float2 a = prow[k];
            float2 w = *(const float2*)(W + (k * 32 + c) * 2);
            acc = cfma(a, w, acc);
        }
        sh_hidden[slot][c] = acc;
    }
    __syncthreads();

    // ---------------- Phase 2: normalize (per l, per channel) ----------------
    {
        int l = tid >> 5, c = tid & 31;
        int off = l * l, n = 2 * l + 1;
        float s = 0.f;
        for (int m = 0; m < n; ++m) {
            float2 v = sh_hidden[off + m][c];
            s += v.x * v.x + v.y * v.y;
        }
        float inv = 1.0f / sqrtf(s);
        for (int m = 0; m < n; ++m) {
            float2 v = sh_hidden[off + m][c];
            sh_hidden[off + m][c] = make_float2(v.x * inv, v.y * inv);
        }
    }
    __syncthreads();

    // ---------------- Layers: CG product + hidden matmul ---------------------
#pragma unroll
    for (int layer = 0; layer < 2; ++layer) {
#pragma unroll
        for (int L = 0; L < 4; ++L) {
            const int ps = c_PS[L];
            const int npair = c_PS[L + 1] - ps;
            const int nM = 2 * L + 1;
            const int nitems = npair * nM * 32;

            // CG products for all pair-blocks of this L -> sh_buf[(p*nM+M)*32+c]
            for (int it = tid; it < nitems; it += 128) {
                int c = it & 31;
                int t2 = it >> 5;
                int M = t2 % nM;
                int p = t2 / nM;
                int l1 = c_P1[ps + p], l2 = c_P2[ps + p];
                int off1 = l1 * l1, off2 = l2 * l2;
                int Mval = M - L;
                float2 acc = make_float2(0.f, 0.f);
                for (int i = 0; i <= 2 * l1; ++i) {
                    int j = Mval - (i - l1) + l2;
                    if (j < 0 || j > 2 * l2) continue;
                    float coef = cg[((((l1 * 4 + l2) * 4 + L) * 7 + i) * 7 + j) * 7 + M];
                    float2 a = sh_hidden[off1 + i][c];
                    float2 bb = sh_hidden[off2 + j][c];
                    float re = a.x * bb.x - a.y * bb.y;
                    float im = a.x * bb.y + a.y * bb.x;
                    acc.x += coef * re;
                    acc.y += coef * im;
                }
                sh_buf[t2 * 32 + c] = acc;
            }
            __syncthreads();

            // Matmul: new_hidden[L*L+M][c_out] = sum_{p,c} prod[p][M][c] * W[(p*32+c)][c_out]
            {
                int c_out = tid & 31, g = tid >> 5;
                const float* W =
                    (layer == 0)
                        ? ((L == 0) ? Wh00 : (L == 1) ? Wh01 : (L == 2) ? Wh02 : Wh03)
                        : ((L == 0) ? Wh10 : (L == 1) ? Wh11 : (L == 2) ? Wh12 : Wh13);
                const int M0 = g, M1 = g + 4;
                const bool h0v = (M0 < nM), h1v = (M1 < nM);
                if (h0v) {
                    float2 acc0 = make_float2(0.f, 0.f);
                    float2 acc1 = make_float2(0.f, 0.f);
                    for (int p = 0; p < npair; ++p) {
                        const float* Wp = W + p * 2048 + c_out * 2;  // (p*32+c)*32*2 + c_out*2
                        const float2* pr0 = &sh_buf[(p * nM + M0) * 32];
                        const float2* pr1 = &sh_buf[(p * nM + (h1v ? M1 : M0)) * 32];
                        for (int c = 0; c < 32; ++c) {
                            float2 w = *(const float2*)(Wp + c * 64);
                            acc0 = cfma(pr0[c], w, acc0);
                            if (h1v) acc1 = cfma(pr1[c], w, acc1);
                        }
                    }
                    sh_new[L * L + M0][c_out] = acc0;
                    if (h1v) sh_new[L * L + M1][c_out] = acc1;
                }
            }
            __syncthreads();
        }

        if (layer == 0) {
            // normalize sh_new -> sh_hidden
            int l = tid >> 5, c = tid & 31;
            int off = l * l, n = 2 * l + 1;
            float s = 0.f;
            for (int m = 0; m < n; ++m) {
                float2 v = sh_new[off + m][c];
                s += v.x * v.x + v.y * v.y;
            }
            float inv = 1.0f / sqrtf(s);
            for (int m = 0; m < n; ++m) {
                float2 v = sh_new[off + m][c];
                sh_hidden[off + m][c] = make_float2(v.x * inv, v.y * inv);
            }
            __syncthreads();
        }
    }

    // ---------------- Final norms + MLP --------------------------------------
    float* shv = (float*)sh_buf;  // [0..127]=norms, [128..383]=h, [384..385]=reduce
    {
        int l = tid >> 5, c = tid & 31;
        int off = l * l, n = 2 * l + 1;
        float s = 0.f;
        for (int m = 0; m < n; ++m) {
            float2 v = sh_new[off + m][c];
            s += v.x * v.x + v.y * v.y;
        }
        shv[tid] = sqrtf(s);  // norms index = l*32 + c = tid
    }
    __syncthreads();

#pragma unroll
    for (int rr = 0; rr < 2; ++rr) {
        int j = tid + rr * 128;
        float acc = b1[j];
        for (int i = 0; i < 128; ++i) acc += shv[i] * W1[i * 256 + j];
        shv[128 + j] = tanhf(acc);
    }
    __syncthreads();

    float partial = shv[128 + tid] * W2[tid] + shv[256 + tid] * W2[tid + 128];
#pragma unroll
    for (int off = 32; off > 0; off >>= 1) partial += __shfl_down(partial, off);
    if ((tid & 63) == 0) shv[384 + (tid >> 6)] = partial;
    __syncthreads();
    if (tid == 0) out[b] = shv[384] + shv[385] + b2[0];
}

extern "C" void kernel_launch(void* const* d_in, const int* in_sizes, int n_in,
                              void* d_out, int out_size, void* d_ws, size_t ws_size,
                              hipStream_t stream) {
    (void)n_in;
    (void)ws_size;
    float* cg = (float*)d_ws;
    hipLaunchKernelGGL(cg_init_kernel, dim3(1), dim3(256), 0, stream, cg);

    const int B = in_sizes[0] / 32;  // part_0 is [B,1,16,2]
    (void)out_size;
    hipLaunchKernelGGL(sph_fwd, dim3(B), dim3(128), 0, stream,
                       (const float*)d_in[0], (const float*)d_in[1],
                       (const float*)d_in[2], (const float*)d_in[3],
                       (const float*)d_in[4], (const float*)d_in[5],
                       (const float*)d_in[6], (const float*)d_in[7],
                       (const float*)d_in[8], (const float*)d_in[9],
                       (const float*)d_in[10], (const float*)d_in[11],
                       (const float*)d_in[12], (const float*)d_in[13],
                       (const float*)d_in[14], (const float*)d_in[15],
                       (const float*)d_in[16], (const float*)d_in[17],
                       (const float*)d_in[18], (const float*)d_in[19],
                       cg, (float*)d_out);
}

// Round 2
// 1389.309 us; speedup vs baseline: 1.0484x; 1.0484x over previous
//
#include <hip/hip_runtime.h>
#include <math.h>

// ---------------------------------------------------------------------------
// Spherical CNN regression forward (MAXL=3, 2 layers, TAU_IN=16, TAU_H=32).
// One 128-thread block per batch element; all per-element state in LDS.
// CG coefficients computed on-device into d_ws by a tiny init kernel:
//   [0, 21952)        dense table [l1][l2][L][i][j][M]
//   [21952, +1092)    compact per-L table: for L: rows r=(pl*nM+M), cols i=0..6
// ---------------------------------------------------------------------------

// Pair tables: for each L, the (l1,l2) blocks in reference concatenation order.
constexpr int kPS[5] = {0, 4, 13, 24, 34};
constexpr unsigned char kP1[34] = {
    0, 1, 2, 3,
    0, 1, 1, 1, 2, 2, 2, 3, 3,
    0, 1, 1, 1, 2, 2, 2, 2, 3, 3, 3,
    0, 1, 1, 2, 2, 2, 3, 3, 3, 3};
constexpr unsigned char kP2[34] = {
    0, 1, 2, 3,
    1, 0, 1, 2, 1, 2, 3, 2, 3,
    2, 1, 2, 3, 0, 1, 2, 3, 1, 2, 3,
    3, 2, 3, 1, 2, 3, 0, 1, 2, 3};
// Compact CG offsets per L: nrows = npair*(2L+1); entries = nrows*7.
constexpr int kCGCoff[5] = {0, 28, 217, 602, 1092};

#define CG_TOTAL (4 * 4 * 4 * 7 * 7 * 7)
#define CGC_TOTAL 1092

__device__ __forceinline__ double dfact(int n) {
    double r = 1.0;
    for (int i = 2; i <= n; ++i) r *= (double)i;
    return r;
}

__global__ void cg_init_kernel(float* __restrict__ cg) {
    float* cgc = cg + CG_TOTAL;
    for (int i = threadIdx.x; i < CG_TOTAL; i += blockDim.x) cg[i] = 0.0f;
    __syncthreads();
    for (int t = threadIdx.x; t < 64; t += blockDim.x) {
        int l1 = t >> 4, l2 = (t >> 2) & 3, L = t & 3;
        if (L < abs(l1 - l2) || L > l1 + l2) continue;
        for (int i = 0; i <= 2 * l1; ++i) {
            int m1 = i - l1;
            for (int j = 0; j <= 2 * l2; ++j) {
                int m2 = j - l2;
                int M = m1 + m2;
                if (M < -L || M > L) continue;
                double pre = sqrt((2.0 * L + 1.0) * dfact(l1 + l2 - L) * dfact(l1 - l2 + L) *
                                  dfact(-l1 + l2 + L) / dfact(l1 + l2 + L + 1));
                pre *= sqrt(dfact(L + M) * dfact(L - M) * dfact(l1 - m1) * dfact(l1 + m1) *
                            dfact(l2 - m2) * dfact(l2 + m2));
                double s = 0.0;
                for (int k = 0; k <= l1 + l2 - L; ++k) {
                    int u2 = l1 - m1 - k, u3 = l2 + m2 - k;
                    int u4 = L - l2 + m1 + k, u5 = L - l1 - m2 + k;
                    if (u2 < 0 || u3 < 0 || u4 < 0 || u5 < 0) continue;
                    double d = dfact(k) * dfact(l1 + l2 - L - k) * dfact(u2) * dfact(u3) *
                               dfact(u4) * dfact(u5);
                    s += ((k & 1) ? -1.0 : 1.0) / d;
                }
                cg[((((l1 * 4 + l2) * 4 + L) * 7 + i) * 7 + j) * 7 + (M + L)] = (float)(pre * s);
            }
        }
    }
    __syncthreads();
    // Compact per-L table
    for (int t = threadIdx.x; t < CGC_TOTAL; t += blockDim.x) {
        int L = 0;
        while (t >= kCGCoff[L + 1]) ++L;
        int rloc = t - kCGCoff[L];
        int r = rloc / 7, i = rloc % 7;
        int nM = 2 * L + 1;
        int pl = r / nM, M = r % nM;
        int l1 = kP1[kPS[L] + pl], l2 = kP2[kPS[L] + pl];
        float v = 0.0f;
        int j = (M - L) - (i - l1) + l2;
        if (i <= 2 * l1 && j >= 0 && j <= 2 * l2)
            v = cg[((((l1 * 4 + l2) * 4 + L) * 7 + i) * 7 + j) * 7 + M];
        cgc[t] = v;
    }
}

__device__ __forceinline__ float2 cfma(float2 a, float2 b, float2 acc) {
    acc.x += a.x * b.x - a.y * b.y;
    acc.y += a.x * b.y + a.y * b.x;
    return acc;
}

// One CG-product + matmul stage for a given L.
//  product rows r = pl*nM + M stored at sh_buf[r*33 + c]  (pad 33 -> bank-clean)
//  matmul: threads (g=tid&3, c_out=tid>>2); g-group owns pairs pl = g+4k;
//  acc[M] registers; width-4 shfl reduction at the end.
template <int L, int PS, int NP>
__device__ __forceinline__ void cg_stage(const float* __restrict__ W,
                                         const float* __restrict__ cgc,
                                         float2 (*sh_hidden)[32], float2 (*sh_new)[32],
                                         float2* sh_buf, int tid) {
    constexpr int nM = 2 * L + 1;
    constexpr int CGO = kCGCoff[L];
    constexpr int NITEMS = NP * nM * 32;

    // ---- CG products ----
    for (int it = tid; it < NITEMS; it += 128) {
        int c = it & 31, t2 = it >> 5;
        int M = t2 % nM, pl = t2 / nM;
        int l1 = kP1[PS + pl], l2 = kP2[PS + pl];
        int off1 = l1 * l1, off2 = l2 * l2;
        float2 acc = make_float2(0.f, 0.f);
        int cbase = CGO + t2 * 7;
        for (int i = 0; i <= 2 * l1; ++i) {
            int j = (M - L) - (i - l1) + l2;
            if (j < 0 || j > 2 * l2) continue;
            float coef = cgc[cbase + i];
            float2 a = sh_hidden[off1 + i][c];
            float2 b = sh_hidden[off2 + j][c];
            acc.x += coef * (a.x * b.x - a.y * b.y);
            acc.y += coef * (a.x * b.y + a.y * b.x);
        }
        sh_buf[t2 * 33 + c] = acc;
    }
    __syncthreads();

    // ---- matmul: new[L*L+M][c_out] = sum_{pl,c} prod[pl][M][c] * W[pl*32+c][c_out]
    {
        const int g = tid & 3, c_out = tid >> 2;
        float2 acc[nM];
#pragma unroll
        for (int M = 0; M < nM; ++M) acc[M] = make_float2(0.f, 0.f);
#pragma unroll
        for (int k = 0; k < (NP + 3) / 4; ++k) {
            int pl = g + 4 * k;
            if (pl < NP) {
                const float* Wp = W + pl * 2048 + c_out * 2;  // ((pl*32+c)*32 + c_out)*2
                const float2* pr = sh_buf + pl * nM * 33;
#pragma unroll 8
                for (int c = 0; c < 32; ++c) {
                    float2 w = *(const float2*)(Wp + c * 64);
#pragma unroll
                    for (int M = 0; M < nM; ++M) acc[M] = cfma(pr[M * 33 + c], w, acc[M]);
                }
            }
        }
#pragma unroll
        for (int M = 0; M < nM; ++M) {
            acc[M].x += __shfl_xor(acc[M].x, 1);
            acc[M].x += __shfl_xor(acc[M].x, 2);
            acc[M].y += __shfl_xor(acc[M].y, 1);
            acc[M].y += __shfl_xor(acc[M].y, 2);
        }
        if (g == 0) {
#pragma unroll
            for (int M = 0; M < nM; ++M) sh_new[L * L + M][c_out] = acc[M];
        }
    }
    __syncthreads();
}

__global__ void __launch_bounds__(128, 3) sph_fwd(
    const float* __restrict__ p0, const float* __restrict__ p1,
    const float* __restrict__ p2, const float* __restrict__ p3,
    const float* __restrict__ Wi0, const float* __restrict__ Wi1,
    const float* __restrict__ Wi2, const float* __restrict__ Wi3,
    const float* __restrict__ Wh00, const float* __restrict__ Wh01,
    const float* __restrict__ Wh02, const float* __restrict__ Wh03,
    const float* __restrict__ Wh10, const float* __restrict__ Wh11,
    const float* __restrict__ Wh12, const float* __restrict__ Wh13,
    const float* __restrict__ W1, const float* __restrict__ b1,
    const float* __restrict__ W2, const float* __restrict__ b2,
    const float* __restrict__ cgc, float* __restrict__ out) {
    // slot = l*l + m_idx (l=0 -> 0, l=1 -> 1..3, l=2 -> 4..8, l=3 -> 9..15)
    __shared__ float2 sh_hidden[16][32];
    __shared__ float2 sh_new[16][32];
    __shared__ float2 sh_buf[2310];  // parts staging / per-L products / MLP scratch

    const int tid = threadIdx.x;
    const int b = blockIdx.x;

    // ---------------- Phase 0: stage parts [16 slots][16 taus] into LDS ------
    for (int idx = tid; idx < 16 * 16; idx += 128) {
        int slot = idx >> 4, k = idx & 15;
        int l = (slot >= 9) + (slot >= 4) + (slot >= 1);
        int m = slot - l * l;
        const float* src = (l == 0) ? p0 : (l == 1) ? p1 : (l == 2) ? p2 : p3;
        src += ((size_t)(b * (2 * l + 1) + m) * 16 + k) * 2;
        sh_buf[idx] = make_float2(src[0], src[1]);
    }
    __syncthreads();

    // ---------------- Phase 1: input matmul (tau_in=16 -> tau_h=32) ----------
#pragma unroll
    for (int r = 0; r < 4; ++r) {
        int oi = tid + 128 * r;
        int slot = oi >> 5, c = oi & 31;
        int l = (slot >= 9) + (slot >= 4) + (slot >= 1);
        const float* W = (l == 0) ? Wi0 : (l == 1) ? Wi1 : (l == 2) ? Wi2 : Wi3;
        const float2* prow = &sh_buf[slot * 16];
        float2 acc = make_float2(0.f, 0.f);
        for (int k = 0; k < 16; ++k) {
            float2 a = prow[k];
            float2 w = *(const float2*)(W + (k * 32 + c) * 2);
            acc = cfma(a, w, acc);
        }
        sh_hidden[slot][c] = acc;
    }
    __syncthreads();

    // ---------------- Phase 2: normalize (per l, per channel) ----------------
    {
        int l = tid >> 5, c = tid & 31;
        int off = l * l, n = 2 * l + 1;
        float s = 0.f;
        for (int m = 0; m < n; ++m) {
            float2 v = sh_hidden[off + m][c];
            s += v.x * v.x + v.y * v.y;
        }
        float inv = 1.0f / sqrtf(s);
        for (int m = 0; m < n; ++m) {
            float2 v = sh_hidden[off + m][c];
            sh_hidden[off + m][c] = make_float2(v.x * inv, v.y * inv);
        }
    }
    __syncthreads();

    // ---------------- Layers ------------------------------------------------
    const float* Wh[2][4] = {{Wh00, Wh01, Wh02, Wh03}, {Wh10, Wh11, Wh12, Wh13}};
#pragma unroll
    for (int layer = 0; layer < 2; ++layer) {
        cg_stage<0, 0, 4>(Wh[layer][0], cgc, sh_hidden, sh_new, sh_buf, tid);
        cg_stage<1, 4, 9>(Wh[layer][1], cgc, sh_hidden, sh_new, sh_buf, tid);
        cg_stage<2, 13, 11>(Wh[layer][2], cgc, sh_hidden, sh_new, sh_buf, tid);
        cg_stage<3, 24, 10>(Wh[layer][3], cgc, sh_hidden, sh_new, sh_buf, tid);

        if (layer == 0) {
            // normalize sh_new -> sh_hidden
            int l = tid >> 5, c = tid & 31;
            int off = l * l, n = 2 * l + 1;
            float s = 0.f;
            for (int m = 0; m < n; ++m) {
                float2 v = sh_new[off + m][c];
                s += v.x * v.x + v.y * v.y;
            }
            float inv = 1.0f / sqrtf(s);
            for (int m = 0; m < n; ++m) {
                float2 v = sh_new[off + m][c];
                sh_hidden[off + m][c] = make_float2(v.x * inv, v.y * inv);
            }
            __syncthreads();
        }
    }

    // ---------------- Final norms + MLP --------------------------------------
    float* shv = (float*)sh_buf;  // [0..127]=norms, [128..383]=h, [384..385]=reduce
    {
        int l = tid >> 5, c = tid & 31;
        int off = l * l, n = 2 * l + 1;
        float s = 0.f;
        for (int m = 0; m < n; ++m) {
            float2 v = sh_new[off + m][c];
            s += v.x * v.x + v.y * v.y;
        }
        shv[tid] = sqrtf(s);  // norms index = l*32 + c = tid
    }
    __syncthreads();

#pragma unroll
    for (int rr = 0; rr < 2; ++rr) {
        int j = tid + rr * 128;
        float acc = b1[j];
        for (int i = 0; i < 128; ++i) acc += shv[i] * W1[i * 256 + j];
        shv[128 + j] = tanhf(acc);
    }
    __syncthreads();

    float partial = shv[128 + tid] * W2[tid] + shv[256 + tid] * W2[tid + 128];
#pragma unroll
    for (int off = 32; off > 0; off >>= 1) partial += __shfl_down(partial, off);
    if ((tid & 63) == 0) shv[384 + (tid >> 6)] = partial;
    __syncthreads();
    if (tid == 0) out[b] = shv[384] + shv[385] + b2[0];
}

extern "C" void kernel_launch(void* const* d_in, const int* in_sizes, int n_in,
                              void* d_out, int out_size, void* d_ws, size_t ws_size,
                              hipStream_t stream) {
    (void)n_in;
    (void)ws_size;
    (void)out_size;
    float* cg = (float*)d_ws;
    hipLaunchKernelGGL(cg_init_kernel, dim3(1), dim3(256), 0, stream, cg);

    const int B = in_sizes[0] / 32;  // part_0 is [B,1,16,2]
    hipLaunchKernelGGL(sph_fwd, dim3(B), dim3(128), 0, stream,
                       (const float*)d_in[0], (const float*)d_in[1],
                       (const float*)d_in[2], (const float*)d_in[3],
                       (const float*)d_in[4], (const float*)d_in[5],
                       (const float*)d_in[6], (const float*)d_in[7],
                       (const float*)d_in[8], (const float*)d_in[9],
                       (const float*)d_in[10], (const float*)d_in[11],
                       (const float*)d_in[12], (const float*)d_in[13],
                       (const float*)d_in[14], (const float*)d_in[15],
                       (const float*)d_in[16], (const float*)d_in[17],
                       (const float*)d_in[18], (const float*)d_in[19],
                       cg + CG_TOTAL, (float*)d_out);
}

// Round 3
// 1001.778 us; speedup vs baseline: 1.4540x; 1.3868x over previous
//
#include <hip/hip_runtime.h>
#include <math.h>

// ---------------------------------------------------------------------------
// Spherical CNN regression forward (MAXL=3, 2 layers, TAU_IN=16, TAU_H=32).
// One 128-thread block per batch element; all per-element state in LDS.
// CG coefficients computed on-device into d_ws by a tiny init kernel:
//   [0, 21952)        dense table [l1][l2][L][i][j][M]
//   [21952, +1092)    compact per-L table: for L: rows r=(pl*nM+M), cols i=0..6
// ---------------------------------------------------------------------------

// Pair tables: for each L, the (l1,l2) blocks in reference concatenation order.
constexpr int kPS[5] = {0, 4, 13, 24, 34};
constexpr unsigned char kP1[34] = {
    0, 1, 2, 3,
    0, 1, 1, 1, 2, 2, 2, 3, 3,
    0, 1, 1, 1, 2, 2, 2, 2, 3, 3, 3,
    0, 1, 1, 2, 2, 2, 3, 3, 3, 3};
constexpr unsigned char kP2[34] = {
    0, 1, 2, 3,
    1, 0, 1, 2, 1, 2, 3, 2, 3,
    2, 1, 2, 3, 0, 1, 2, 3, 1, 2, 3,
    3, 2, 3, 1, 2, 3, 0, 1, 2, 3};
// Compact CG offsets per L: nrows = npair*(2L+1); entries = nrows*7.
constexpr int kCGCoff[5] = {0, 28, 217, 602, 1092};

#define CG_TOTAL (4 * 4 * 4 * 7 * 7 * 7)
#define CGC_TOTAL 1092

__device__ __forceinline__ double dfact(int n) {
    double r = 1.0;
    for (int i = 2; i <= n; ++i) r *= (double)i;
    return r;
}

__global__ void cg_init_kernel(float* __restrict__ cg) {
    float* cgc = cg + CG_TOTAL;
    for (int i = threadIdx.x; i < CG_TOTAL; i += blockDim.x) cg[i] = 0.0f;
    __syncthreads();
    for (int t = threadIdx.x; t < 64; t += blockDim.x) {
        int l1 = t >> 4, l2 = (t >> 2) & 3, L = t & 3;
        if (L < abs(l1 - l2) || L > l1 + l2) continue;
        for (int i = 0; i <= 2 * l1; ++i) {
            int m1 = i - l1;
            for (int j = 0; j <= 2 * l2; ++j) {
                int m2 = j - l2;
                int M = m1 + m2;
                if (M < -L || M > L) continue;
                double pre = sqrt((2.0 * L + 1.0) * dfact(l1 + l2 - L) * dfact(l1 - l2 + L) *
                                  dfact(-l1 + l2 + L) / dfact(l1 + l2 + L + 1));
                pre *= sqrt(dfact(L + M) * dfact(L - M) * dfact(l1 - m1) * dfact(l1 + m1) *
                            dfact(l2 - m2) * dfact(l2 + m2));
                double s = 0.0;
                for (int k = 0; k <= l1 + l2 - L; ++k) {
                    int u2 = l1 - m1 - k, u3 = l2 + m2 - k;
                    int u4 = L - l2 + m1 + k, u5 = L - l1 - m2 + k;
                    if (u2 < 0 || u3 < 0 || u4 < 0 || u5 < 0) continue;
                    double d = dfact(k) * dfact(l1 + l2 - L - k) * dfact(u2) * dfact(u3) *
                               dfact(u4) * dfact(u5);
                    s += ((k & 1) ? -1.0 : 1.0) / d;
                }
                cg[((((l1 * 4 + l2) * 4 + L) * 7 + i) * 7 + j) * 7 + (M + L)] = (float)(pre * s);
            }
        }
    }
    __syncthreads();
    // Compact per-L table
    for (int t = threadIdx.x; t < CGC_TOTAL; t += blockDim.x) {
        int L = 0;
        while (t >= kCGCoff[L + 1]) ++L;
        int rloc = t - kCGCoff[L];
        int r = rloc / 7, i = rloc % 7;
        int nM = 2 * L + 1;
        int pl = r / nM, M = r % nM;
        int l1 = kP1[kPS[L] + pl], l2 = kP2[kPS[L] + pl];
        float v = 0.0f;
        int j = (M - L) - (i - l1) + l2;
        if (i <= 2 * l1 && j >= 0 && j <= 2 * l2)
            v = cg[((((l1 * 4 + l2) * 4 + L) * 7 + i) * 7 + j) * 7 + M];
        cgc[t] = v;
    }
}

__device__ __forceinline__ float2 cfma(float2 a, float2 b, float2 acc) {
    acc.x += a.x * b.x - a.y * b.y;
    acc.y += a.x * b.y + a.y * b.x;
    return acc;
}

// Apply OP(M) for M = 0..nM-1 at compile time (named-register friendly).
#define FOR_M(OP)                    \
    do {                             \
        OP(0);                       \
        if constexpr (nM > 1) {      \
            OP(1);                   \
            OP(2);                   \
        }                            \
        if constexpr (nM > 3) {      \
            OP(3);                   \
            OP(4);                   \
        }                            \
        if constexpr (nM > 5) {      \
            OP(5);                   \
            OP(6);                   \
        }                            \
    } while (0)

// One CG-product + matmul stage for a given L.
//  product rows r = pl*nM + M stored at sh_buf[r*33 + c]  (pad 33 -> bank-clean)
//  matmul: threads (g=tid&3, c_out=tid>>2); g-group owns pairs pl = g+4k;
//  NAMED accumulators a0..a6 (rule #20: arrays would go to scratch);
//  width-4 shfl reduction at the end.
template <int L, int PS, int NP>
__device__ __forceinline__ void cg_stage(const float* __restrict__ W,
                                         const float* __restrict__ cgc,
                                         float2 (*sh_hidden)[32], float2 (*sh_new)[32],
                                         float2* sh_buf, int tid) {
    constexpr int nM = 2 * L + 1;
    constexpr int CGO = kCGCoff[L];
    constexpr int NITEMS = NP * nM * 32;

    // ---- CG products ----
    for (int it = tid; it < NITEMS; it += 128) {
        int c = it & 31, t2 = it >> 5;
        int M = t2 % nM, pl = t2 / nM;
        int l1 = kP1[PS + pl], l2 = kP2[PS + pl];
        int off1 = l1 * l1, off2 = l2 * l2;
        float2 acc = make_float2(0.f, 0.f);
        int cbase = CGO + t2 * 7;
        for (int i = 0; i <= 2 * l1; ++i) {
            int j = (M - L) - (i - l1) + l2;
            if (j < 0 || j > 2 * l2) continue;
            float coef = cgc[cbase + i];
            float2 a = sh_hidden[off1 + i][c];
            float2 b = sh_hidden[off2 + j][c];
            acc.x += coef * (a.x * b.x - a.y * b.y);
            acc.y += coef * (a.x * b.y + a.y * b.x);
        }
        sh_buf[t2 * 33 + c] = acc;
    }
    __syncthreads();

    // ---- matmul: new[L*L+M][c_out] = sum_{pl,c} prod[pl][M][c] * W[pl*32+c][c_out]
    {
        const int g = tid & 3, c_out = tid >> 2;
        const float2 z = make_float2(0.f, 0.f);
        float2 a0 = z, a1 = z, a2 = z, a3 = z, a4 = z, a5 = z, a6 = z;
#pragma unroll
        for (int k = 0; k < (NP + 3) / 4; ++k) {
            int pl = g + 4 * k;
            if (pl < NP) {
                const float* Wp = W + pl * 2048 + c_out * 2;  // ((pl*32+c)*32 + c_out)*2
                const float2* pr = sh_buf + pl * nM * 33;
#pragma unroll 8
                for (int c = 0; c < 32; ++c) {
                    float2 w = *(const float2*)(Wp + c * 64);
#define CFMA_M(M) a##M = cfma(pr[M * 33 + c], w, a##M)
                    FOR_M(CFMA_M);
#undef CFMA_M
                }
            }
        }
#define RED_M(M)                               \
    do {                                       \
        a##M.x += __shfl_xor(a##M.x, 1);       \
        a##M.x += __shfl_xor(a##M.x, 2);       \
        a##M.y += __shfl_xor(a##M.y, 1);       \
        a##M.y += __shfl_xor(a##M.y, 2);       \
    } while (0)
        FOR_M(RED_M);
#undef RED_M
        if (g == 0) {
#define ST_M(M) sh_new[L * L + M][c_out] = a##M
            FOR_M(ST_M);
#undef ST_M
        }
    }
    __syncthreads();
}

__global__ void __launch_bounds__(128) sph_fwd(
    const float* __restrict__ p0, const float* __restrict__ p1,
    const float* __restrict__ p2, const float* __restrict__ p3,
    const float* __restrict__ Wi0, const float* __restrict__ Wi1,
    const float* __restrict__ Wi2, const float* __restrict__ Wi3,
    const float* __restrict__ Wh00, const float* __restrict__ Wh01,
    const float* __restrict__ Wh02, const float* __restrict__ Wh03,
    const float* __restrict__ Wh10, const float* __restrict__ Wh11,
    const float* __restrict__ Wh12, const float* __restrict__ Wh13,
    const float* __restrict__ W1, const float* __restrict__ b1,
    const float* __restrict__ W2, const float* __restrict__ b2,
    const float* __restrict__ cgc, float* __restrict__ out) {
    // slot = l*l + m_idx (l=0 -> 0, l=1 -> 1..3, l=2 -> 4..8, l=3 -> 9..15)
    __shared__ float2 sh_hidden[16][32];
    __shared__ float2 sh_new[16][32];
    __shared__ float2 sh_buf[2310];  // parts staging / per-L products / MLP scratch

    const int tid = threadIdx.x;
    const int b = blockIdx.x;

    // ---------------- Phase 0: stage parts [16 slots][16 taus] into LDS ------
    for (int idx = tid; idx < 16 * 16; idx += 128) {
        int slot = idx >> 4, k = idx & 15;
        int l = (slot >= 9) + (slot >= 4) + (slot >= 1);
        int m = slot - l * l;
        const float* src = (l == 0) ? p0 : (l == 1) ? p1 : (l == 2) ? p2 : p3;
        src += ((size_t)(b * (2 * l + 1) + m) * 16 + k) * 2;
        sh_buf[idx] = make_float2(src[0], src[1]);
    }
    __syncthreads();

    // ---------------- Phase 1: input matmul (tau_in=16 -> tau_h=32) ----------
#pragma unroll
    for (int r = 0; r < 4; ++r) {
        int oi = tid + 128 * r;
        int slot = oi >> 5, c = oi & 31;
        int l = (slot >= 9) + (slot >= 4) + (slot >= 1);
        const float* W = (l == 0) ? Wi0 : (l == 1) ? Wi1 : (l == 2) ? Wi2 : Wi3;
        const float2* prow = &sh_buf[slot * 16];
        float2 acc = make_float2(0.f, 0.f);
        for (int k = 0; k < 16; ++k) {
            float2 a = prow[k];
            float2 w = *(const float2*)(W + (k * 32 + c) * 2);
            acc = cfma(a, w, acc);
        }
        sh_hidden[slot][c] = acc;
    }
    __syncthreads();

    // ---------------- Phase 2: normalize (per l, per channel) ----------------
    {
        int l = tid >> 5, c = tid & 31;
        int off = l * l, n = 2 * l + 1;
        float s = 0.f;
        for (int m = 0; m < n; ++m) {
            float2 v = sh_hidden[off + m][c];
            s += v.x * v.x + v.y * v.y;
        }
        float inv = 1.0f / sqrtf(s);
        for (int m = 0; m < n; ++m) {
            float2 v = sh_hidden[off + m][c];
            sh_hidden[off + m][c] = make_float2(v.x * inv, v.y * inv);
        }
    }
    __syncthreads();

    // ---------------- Layer 0 ------------------------------------------------
    cg_stage<0, 0, 4>(Wh00, cgc, sh_hidden, sh_new, sh_buf, tid);
    cg_stage<1, 4, 9>(Wh01, cgc, sh_hidden, sh_new, sh_buf, tid);
    cg_stage<2, 13, 11>(Wh02, cgc, sh_hidden, sh_new, sh_buf, tid);
    cg_stage<3, 24, 10>(Wh03, cgc, sh_hidden, sh_new, sh_buf, tid);

    // normalize sh_new -> sh_hidden
    {
        int l = tid >> 5, c = tid & 31;
        int off = l * l, n = 2 * l + 1;
        float s = 0.f;
        for (int m = 0; m < n; ++m) {
            float2 v = sh_new[off + m][c];
            s += v.x * v.x + v.y * v.y;
        }
        float inv = 1.0f / sqrtf(s);
        for (int m = 0; m < n; ++m) {
            float2 v = sh_new[off + m][c];
            sh_hidden[off + m][c] = make_float2(v.x * inv, v.y * inv);
        }
    }
    __syncthreads();

    // ---------------- Layer 1 ------------------------------------------------
    cg_stage<0, 0, 4>(Wh10, cgc, sh_hidden, sh_new, sh_buf, tid);
    cg_stage<1, 4, 9>(Wh11, cgc, sh_hidden, sh_new, sh_buf, tid);
    cg_stage<2, 13, 11>(Wh12, cgc, sh_hidden, sh_new, sh_buf, tid);
    cg_stage<3, 24, 10>(Wh13, cgc, sh_hidden, sh_new, sh_buf, tid);

    // ---------------- Final norms + MLP --------------------------------------
    float* shv = (float*)sh_buf;  // [0..127]=norms, [128..383]=h, [384..385]=reduce
    {
        int l = tid >> 5, c = tid & 31;
        int off = l * l, n = 2 * l + 1;
        float s = 0.f;
        for (int m = 0; m < n; ++m) {
            float2 v = sh_new[off + m][c];
            s += v.x * v.x + v.y * v.y;
        }
        shv[tid] = sqrtf(s);  // norms index = l*32 + c = tid
    }
    __syncthreads();

#pragma unroll
    for (int rr = 0; rr < 2; ++rr) {
        int j = tid + rr * 128;
        float acc = b1[j];
        for (int i = 0; i < 128; ++i) acc += shv[i] * W1[i * 256 + j];
        shv[128 + j] = tanhf(acc);
    }
    __syncthreads();

    float partial = shv[128 + tid] * W2[tid] + shv[256 + tid] * W2[tid + 128];
#pragma unroll
    for (int off = 32; off > 0; off >>= 1) partial += __shfl_down(partial, off);
    if ((tid & 63) == 0) shv[384 + (tid >> 6)] = partial;
    __syncthreads();
    if (tid == 0) out[b] = shv[384] + shv[385] + b2[0];
}

extern "C" void kernel_launch(void* const* d_in, const int* in_sizes, int n_in,
                              void* d_out, int out_size, void* d_ws, size_t ws_size,
                              hipStream_t stream) {
    (void)n_in;
    (void)ws_size;
    (void)out_size;
    float* cg = (float*)d_ws;
    hipLaunchKernelGGL(cg_init_kernel, dim3(1), dim3(256), 0, stream, cg);

    const int B = in_sizes[0] / 32;  // part_0 is [B,1,16,2]
    hipLaunchKernelGGL(sph_fwd, dim3(B), dim3(128), 0, stream,
                       (const float*)d_in[0], (const float*)d_in[1],
                       (const float*)d_in[2], (const float*)d_in[3],
                       (const float*)d_in[4], (const float*)d_in[5],
                       (const float*)d_in[6], (const float*)d_in[7],
                       (const float*)d_in[8], (const float*)d_in[9],
                       (const float*)d_in[10], (const float*)d_in[11],
                       (const float*)d_in[12], (const float*)d_in[13],
                       (const float*)d_in[14], (const float*)d_in[15],
                       (const float*)d_in[16], (const float*)d_in[17],
                       (const float*)d_in[18], (const float*)d_in[19],
                       cg + CG_TOTAL, (float*)d_out);
}

// Round 4
// 907.702 us; speedup vs baseline: 1.6047x; 1.1036x over previous
//
#include <hip/hip_runtime.h>
#include <hip/hip_fp16.h>
#include <math.h>

// ---------------------------------------------------------------------------
// Spherical CNN regression forward (MAXL=3, 2 layers, TAU_IN=16, TAU_H=32).
// One 128-thread block per batch element; all per-element state in LDS.
// CG coefficients computed on-device into d_ws by a tiny init kernel:
//   [0, 21952)        dense table [l1][l2][L][i][j][M]
//   [21952, +1092)    compact per-L table: rows r=(pl*nM+M), cols i=0..6
//                     (entries are 0.0 for invalid (i,j) -> branch-free use)
// ---------------------------------------------------------------------------

// Pair tables: for each L, the (l1,l2) blocks in reference concatenation order.
constexpr int kPS[5] = {0, 4, 13, 24, 34};
constexpr unsigned char kP1[34] = {
    0, 1, 2, 3,
    0, 1, 1, 1, 2, 2, 2, 3, 3,
    0, 1, 1, 1, 2, 2, 2, 2, 3, 3, 3,
    0, 1, 1, 2, 2, 2, 3, 3, 3, 3};
constexpr unsigned char kP2[34] = {
    0, 1, 2, 3,
    1, 0, 1, 2, 1, 2, 3, 2, 3,
    2, 1, 2, 3, 0, 1, 2, 3, 1, 2, 3,
    3, 2, 3, 1, 2, 3, 0, 1, 2, 3};
// Compact CG offsets per L: nrows = npair*(2L+1); entries = nrows*7.
constexpr int kCGCoff[5] = {0, 28, 217, 602, 1092};

#define CG_TOTAL (4 * 4 * 4 * 7 * 7 * 7)
#define CGC_TOTAL 1092

__device__ __forceinline__ double dfact(int n) {
    double r = 1.0;
    for (int i = 2; i <= n; ++i) r *= (double)i;
    return r;
}

__global__ void cg_init_kernel(float* __restrict__ cg) {
    float* cgc = cg + CG_TOTAL;
    for (int i = threadIdx.x; i < CG_TOTAL; i += blockDim.x) cg[i] = 0.0f;
    __syncthreads();
    for (int t = threadIdx.x; t < 64; t += blockDim.x) {
        int l1 = t >> 4, l2 = (t >> 2) & 3, L = t & 3;
        if (L < abs(l1 - l2) || L > l1 + l2) continue;
        for (int i = 0; i <= 2 * l1; ++i) {
            int m1 = i - l1;
            for (int j = 0; j <= 2 * l2; ++j) {
                int m2 = j - l2;
                int M = m1 + m2;
                if (M < -L || M > L) continue;
                double pre = sqrt((2.0 * L + 1.0) * dfact(l1 + l2 - L) * dfact(l1 - l2 + L) *
                                  dfact(-l1 + l2 + L) / dfact(l1 + l2 + L + 1));
                pre *= sqrt(dfact(L + M) * dfact(L - M) * dfact(l1 - m1) * dfact(l1 + m1) *
                            dfact(l2 - m2) * dfact(l2 + m2));
                double s = 0.0;
                for (int k = 0; k <= l1 + l2 - L; ++k) {
                    int u2 = l1 - m1 - k, u3 = l2 + m2 - k;
                    int u4 = L - l2 + m1 + k, u5 = L - l1 - m2 + k;
                    if (u2 < 0 || u3 < 0 || u4 < 0 || u5 < 0) continue;
                    double d = dfact(k) * dfact(l1 + l2 - L - k) * dfact(u2) * dfact(u3) *
                               dfact(u4) * dfact(u5);
                    s += ((k & 1) ? -1.0 : 1.0) / d;
                }
                cg[((((l1 * 4 + l2) * 4 + L) * 7 + i) * 7 + j) * 7 + (M + L)] = (float)(pre * s);
            }
        }
    }
    __syncthreads();
    // Compact per-L table (0.0 for invalid (i,j) combos).
    for (int t = threadIdx.x; t < CGC_TOTAL; t += blockDim.x) {
        int L = 0;
        while (t >= kCGCoff[L + 1]) ++L;
        int rloc = t - kCGCoff[L];
        int r = rloc / 7, i = rloc % 7;
        int nM = 2 * L + 1;
        int pl = r / nM, M = r % nM;
        int l1 = kP1[kPS[L] + pl], l2 = kP2[kPS[L] + pl];
        float v = 0.0f;
        int j = (M - L) - (i - l1) + l2;
        if (i <= 2 * l1 && j >= 0 && j <= 2 * l2)
            v = cg[((((l1 * 4 + l2) * 4 + L) * 7 + i) * 7 + j) * 7 + M];
        cgc[t] = v;
    }
}

// Apply OP(M) for M = 0..nM-1 at compile time (named-register friendly).
#define FOR_M(OP)                    \
    do {                             \
        OP(0);                       \
        if constexpr (nM > 1) {      \
            OP(1);                   \
            OP(2);                   \
        }                            \
        if constexpr (nM > 3) {      \
            OP(3);                   \
            OP(4);                   \
        }                            \
        if constexpr (nM > 5) {      \
            OP(5);                   \
            OP(6);                   \
        }                            \
    } while (0)

// One CG-product + matmul stage for a given L.
//  product rows r = pl*nM + M stored as __half2 at prods[r*33 + c] (pad 33)
//  product inner loop: branch-free 7-step unroll (coef==0 masks invalid i/j)
//  matmul: threads (g=tid&3, c_out=tid>>2); g-group owns pairs pl = g+4k;
//  NAMED accumulators a0..a6 (rule #20); width-4 shfl reduction at the end.
template <int L, int PS, int NP>
__device__ __forceinline__ void cg_stage(const float* __restrict__ W,
                                         const float* __restrict__ cgc,
                                         float2 (*sh_hidden)[32], float2 (*sh_new)[32],
                                         __half2* prods, int tid) {
    constexpr int nM = 2 * L + 1;
    constexpr int CGO = kCGCoff[L];
    constexpr int NITEMS = NP * nM * 32;

    // ---- CG products ----
    for (int it = tid; it < NITEMS; it += 128) {
        int c = it & 31, t2 = it >> 5;
        int M = t2 % nM, pl = t2 / nM;
        int l1 = kP1[PS + pl], l2 = kP2[PS + pl];
        int off1 = l1 * l1, off2 = l2 * l2;
        int jb = (M - L) + l1 + l2;  // j = jb - i
        int jmax = 2 * l2;
        float2 acc = make_float2(0.f, 0.f);
        int cbase = CGO + t2 * 7;
#pragma unroll
        for (int i = 0; i < 7; ++i) {
            float coef = cgc[cbase + i];
            int j = jb - i;
            j = (j < 0) ? 0 : ((j > jmax) ? jmax : j);
            float2 a = sh_hidden[off1 + i][c];  // off1+i <= 15 always
            float2 b = sh_hidden[off2 + j][c];
            acc.x += coef * (a.x * b.x - a.y * b.y);
            acc.y += coef * (a.x * b.y + a.y * b.x);
        }
        prods[t2 * 33 + c] = __float22half2_rn(acc);
    }
    __syncthreads();

    // ---- matmul: new[L*L+M][c_out] = sum_{pl,c} prod[pl][M][c] * W[pl*32+c][c_out]
    {
        const int g = tid & 3, c_out = tid >> 2;
        const float2 z = make_float2(0.f, 0.f);
        float2 a0 = z, a1 = z, a2 = z, a3 = z, a4 = z, a5 = z, a6 = z;
#pragma unroll
        for (int k = 0; k < (NP + 3) / 4; ++k) {
            int pl = g + 4 * k;
            if (pl < NP) {
                const float* Wp = W + pl * 2048 + c_out * 2;  // ((pl*32+c)*32 + c_out)*2
                const __half2* pr = prods + pl * nM * 33;
#pragma unroll 8
                for (int c = 0; c < 32; ++c) {
                    float2 w = *(const float2*)(Wp + c * 64);
#define CFMA_M(M)                                              \
    do {                                                       \
        float2 pf = __half22float2(pr[M * 33 + c]);            \
        a##M.x += pf.x * w.x - pf.y * w.y;                     \
        a##M.y += pf.x * w.y + pf.y * w.x;                     \
    } while (0)
                    FOR_M(CFMA_M);
#undef CFMA_M
                }
            }
        }
#define RED_M(M)                               \
    do {                                       \
        a##M.x += __shfl_xor(a##M.x, 1);       \
        a##M.x += __shfl_xor(a##M.x, 2);       \
        a##M.y += __shfl_xor(a##M.y, 1);       \
        a##M.y += __shfl_xor(a##M.y, 2);       \
    } while (0)
        FOR_M(RED_M);
#undef RED_M
        if (g == 0) {
#define ST_M(M) sh_new[L * L + M][c_out] = a##M
            FOR_M(ST_M);
#undef ST_M
        }
    }
    __syncthreads();
}

__global__ void __launch_bounds__(128) sph_fwd(
    const float* __restrict__ p0, const float* __restrict__ p1,
    const float* __restrict__ p2, const float* __restrict__ p3,
    const float* __restrict__ Wi0, const float* __restrict__ Wi1,
    const float* __restrict__ Wi2, const float* __restrict__ Wi3,
    const float* __restrict__ Wh00, const float* __restrict__ Wh01,
    const float* __restrict__ Wh02, const float* __restrict__ Wh03,
    const float* __restrict__ Wh10, const float* __restrict__ Wh11,
    const float* __restrict__ Wh12, const float* __restrict__ Wh13,
    const float* __restrict__ W1, const float* __restrict__ b1,
    const float* __restrict__ W2, const float* __restrict__ b2,
    const float* __restrict__ cgc, float* __restrict__ out) {
    // slot = l*l + m_idx (l=0 -> 0, l=1 -> 1..3, l=2 -> 4..8, l=3 -> 9..15)
    __shared__ float2 sh_hidden[16][32];
    __shared__ float2 sh_new[16][32];
    // Overlaid scratch: parts staging (2 KB) / f16 products (9.24 KB) / MLP (1.6 KB)
    __shared__ __align__(16) unsigned char sh_raw[9248];

    const int tid = threadIdx.x;
    const int b = blockIdx.x;

    // ---------------- Phase 0: stage parts [16 slots][16 taus] into LDS ------
    {
        float2* stg = (float2*)sh_raw;
        for (int idx = tid; idx < 16 * 16; idx += 128) {
            int slot = idx >> 4, k = idx & 15;
            int l = (slot >= 9) + (slot >= 4) + (slot >= 1);
            int m = slot - l * l;
            const float* src = (l == 0) ? p0 : (l == 1) ? p1 : (l == 2) ? p2 : p3;
            src += ((size_t)(b * (2 * l + 1) + m) * 16 + k) * 2;
            stg[idx] = make_float2(src[0], src[1]);
        }
    }
    __syncthreads();

    // ---------------- Phase 1: input matmul (tau_in=16 -> tau_h=32) ----------
#pragma unroll
    for (int r = 0; r < 4; ++r) {
        const float2* stg = (const float2*)sh_raw;
        int oi = tid + 128 * r;
        int slot = oi >> 5, c = oi & 31;
        int l = (slot >= 9) + (slot >= 4) + (slot >= 1);
        const float* W = (l == 0) ? Wi0 : (l == 1) ? Wi1 : (l == 2) ? Wi2 : Wi3;
        const float2* prow = &stg[slot * 16];
        float2 acc = make_float2(0.f, 0.f);
        for (int k = 0; k < 16; ++k) {
            float2 a = prow[k];
            float2 w = *(const float2*)(W + (k * 32 + c) * 2);
            acc.x += a.x * w.x - a.y * w.y;
            acc.y += a.x * w.y + a.y * w.x;
        }
        sh_hidden[slot][c] = acc;
    }
    __syncthreads();

    // ---------------- Phase 2: normalize (per l, per channel) ----------------
    {
        int l = tid >> 5, c = tid & 31;
        int off = l * l, n = 2 * l + 1;
        float s = 0.f;
        for (int m = 0; m < n; ++m) {
            float2 v = sh_hidden[off + m][c];
            s += v.x * v.x + v.y * v.y;
        }
        float inv = 1.0f / sqrtf(s);
        for (int m = 0; m < n; ++m) {
            float2 v = sh_hidden[off + m][c];
            sh_hidden[off + m][c] = make_float2(v.x * inv, v.y * inv);
        }
    }
    __syncthreads();

    __half2* prods = (__half2*)sh_raw;

    // ---------------- Layer 0 ------------------------------------------------
    cg_stage<0, 0, 4>(Wh00, cgc, sh_hidden, sh_new, prods, tid);
    cg_stage<1, 4, 9>(Wh01, cgc, sh_hidden, sh_new, prods, tid);
    cg_stage<2, 13, 11>(Wh02, cgc, sh_hidden, sh_new, prods, tid);
    cg_stage<3, 24, 10>(Wh03, cgc, sh_hidden, sh_new, prods, tid);

    // normalize sh_new -> sh_hidden
    {
        int l = tid >> 5, c = tid & 31;
        int off = l * l, n = 2 * l + 1;
        float s = 0.f;
        for (int m = 0; m < n; ++m) {
            float2 v = sh_new[off + m][c];
            s += v.x * v.x + v.y * v.y;
        }
        float inv = 1.0f / sqrtf(s);
        for (int m = 0; m < n; ++m) {
            float2 v = sh_new[off + m][c];
            sh_hidden[off + m][c] = make_float2(v.x * inv, v.y * inv);
        }
    }
    __syncthreads();

    // ---------------- Layer 1 ------------------------------------------------
    cg_stage<0, 0, 4>(Wh10, cgc, sh_hidden, sh_new, prods, tid);
    cg_stage<1, 4, 9>(Wh11, cgc, sh_hidden, sh_new, prods, tid);
    cg_stage<2, 13, 11>(Wh12, cgc, sh_hidden, sh_new, prods, tid);
    cg_stage<3, 24, 10>(Wh13, cgc, sh_hidden, sh_new, prods, tid);

    // ---------------- Final norms + MLP --------------------------------------
    float* shv = (float*)sh_raw;  // [0..127]=norms, [128..383]=h, [384..385]=reduce
    {
        int l = tid >> 5, c = tid & 31;
        int off = l * l, n = 2 * l + 1;
        float s = 0.f;
        for (int m = 0; m < n; ++m) {
            float2 v = sh_new[off + m][c];
            s += v.x * v.x + v.y * v.y;
        }
        shv[tid] = sqrtf(s);  // norms index = l*32 + c = tid
    }
    __syncthreads();

#pragma unroll
    for (int rr = 0; rr < 2; ++rr) {
        int j = tid + rr * 128;
        float acc = b1[j];
        for (int i = 0; i < 128; ++i) acc += shv[i] * W1[i * 256 + j];
        shv[128 + j] = tanhf(acc);
    }
    __syncthreads();

    float partial = shv[128 + tid] * W2[tid] + shv[256 + tid] * W2[tid + 128];
#pragma unroll
    for (int off = 32; off > 0; off >>= 1) partial += __shfl_down(partial, off);
    if ((tid & 63) == 0) shv[384 + (tid >> 6)] = partial;
    __syncthreads();
    if (tid == 0) out[b] = shv[384] + shv[385] + b2[0];
}

extern "C" void kernel_launch(void* const* d_in, const int* in_sizes, int n_in,
                              void* d_out, int out_size, void* d_ws, size_t ws_size,
                              hipStream_t stream) {
    (void)n_in;
    (void)ws_size;
    (void)out_size;
    float* cg = (float*)d_ws;
    hipLaunchKernelGGL(cg_init_kernel, dim3(1), dim3(256), 0, stream, cg);

    const int B = in_sizes[0] / 32;  // part_0 is [B,1,16,2]
    hipLaunchKernelGGL(sph_fwd, dim3(B), dim3(128), 0, stream,
                       (const float*)d_in[0], (const float*)d_in[1],
                       (const float*)d_in[2], (const float*)d_in[3],
                       (const float*)d_in[4], (const float*)d_in[5],
                       (const float*)d_in[6], (const float*)d_in[7],
                       (const float*)d_in[8], (const float*)d_in[9],
                       (const float*)d_in[10], (const float*)d_in[11],
                       (const float*)d_in[12], (const float*)d_in[13],
                       (const float*)d_in[14], (const float*)d_in[15],
                       (const float*)d_in[16], (const float*)d_in[17],
                       (const float*)d_in[18], (const float*)d_in[19],
                       cg + CG_TOTAL, (float*)d_out);
}